// Round 8
// baseline (160.809 us; speedup 1.0000x reference)
//
#include <hip/hip_runtime.h>

// ---------------- types / helpers ----------------
typedef __attribute__((ext_vector_type(16))) float f32x16;
typedef __attribute__((ext_vector_type(8))) __bf16 bf16x8;
typedef __attribute__((ext_vector_type(8))) unsigned short u16x8;

__device__ __forceinline__ unsigned short f2bf(float f) {
    unsigned int u = __float_as_uint(f);
    u += 0x7fffu + ((u >> 16) & 1u);       // RTNE
    return (unsigned short)(u >> 16);
}

__device__ __forceinline__ float softplus_f(float x) {
    float e = __expf(-fabsf(x));
    return fmaxf(x, 0.0f) + __logf(1.0f + e);
}

// ---------------- repack into FRAGMENT-MAJOR layout ----------------
// Output: [group of 32 rows][kpair 0..23][lane 0..63][8 bf16]  where
// lane = h*32 + (row%32), kc = kpair*2 + h. A wave's MFMA fragment load is then
// ONE global_load_dwordx4 at wave-uniform base + lane*16 (perfectly coalesced).
// A-part (2048 t-rows, 64 groups) precedes W-part (16384 node-rows, 512 groups).
#define REPACK_NB 2
#define REPACK_BLOCKS 1728
__global__ __launch_bounds__(256) void repack(
        const float* __restrict__ x, const float* __restrict__ iv,
        const float* __restrict__ temb,
        const float* __restrict__ Wa, const float* __restrict__ Wi,
        const float* __restrict__ Wt,
        unsigned short* __restrict__ Abf2 /* Wbf2 follows contiguously */) {
    const int stride = REPACK_BLOCKS * 256;
    const int tid0 = blockIdx.x * 256 + threadIdx.x;
    float4 f[REPACK_NB][2];
    int dsto[REPACK_NB];
    #pragma unroll
    for (int c = 0; c < REPACK_NB; ++c) {
        const int idx = tid0 + c * stride;          // input chunk id (row-major)
        const bool isA = idx < 98304;
        const int widx = isA ? idx : idx - 98304;
        const int row = widx / 48;
        const int kc  = widx % 48;
        const int kk  = kc * 8;
        // coalesced f32 reads (same as before)
        const float* p0 = isA ? (x    + (size_t)row * 256) : (Wa + (size_t)row * 256);
        const float* p1 = isA ? (iv   + (size_t)row * 64)  : (Wi + (size_t)row * 64);
        const float* p2 = isA ? (temb + (size_t)(row & 127) * 64) : (Wt + (size_t)row * 64);
        const float* src = (kk < 256) ? (p0 + kk) : ((kk < 320) ? (p1 + kk - 256) : (p2 + kk - 320));
        f[c][0] = ((const float4*)src)[0];
        f[c][1] = ((const float4*)src)[1];
        // fragment-major destination chunk index
        const int g  = row >> 5;
        const int r31 = row & 31;
        const int kp = kc >> 1;
        const int h  = kc & 1;
        const int o  = ((g * 24 + kp) * 64) + h * 32 + r31;
        dsto[c] = (isA ? o : (98304 + o));
    }
    #pragma unroll
    for (int c = 0; c < REPACK_NB; ++c) {
        u16x8 o;
        o[0] = f2bf(f[c][0].x); o[1] = f2bf(f[c][0].y); o[2] = f2bf(f[c][0].z); o[3] = f2bf(f[c][0].w);
        o[4] = f2bf(f[c][1].x); o[5] = f2bf(f[c][1].y); o[6] = f2bf(f[c][1].z); o[7] = f2bf(f[c][1].w);
        *(u16x8*)(Abf2 + (size_t)dsto[c] * 8) = o;   // scattered 16B store (fire-and-forget)
    }
}

// ---------------- tproj: tp3T[4096][128], tp2T[1024][128], tp1T[256][128] (t contiguous) ----
__global__ __launch_bounds__(256) void tproj(
        const float* __restrict__ temb,
        const float* __restrict__ tW3, const float* __restrict__ tb3,
        const float* __restrict__ tW2, const float* __restrict__ tb2,
        const float* __restrict__ tW1, const float* __restrict__ tb1,
        float* __restrict__ tp3T, float* __restrict__ tp2T, float* __restrict__ tp1T) {
    __shared__ float se[32 * 64];
    const int tid = threadIdx.x;
    const int tbase = blockIdx.y * 32;
    for (int i = tid; i < 32 * 64; i += 256) se[i] = temb[tbase * 64 + i];
    __syncthreads();
    const int j = blockIdx.x * 64 + (tid >> 2);
    const float* W; const float* bias; float* outp; int jl;
    if      (j < 4096) { W = tW3; bias = tb3; outp = tp3T; jl = j; }
    else if (j < 5120) { W = tW2; bias = tb2; outp = tp2T; jl = j - 4096; }
    else               { W = tW1; bias = tb1; outp = tp1T; jl = j - 5120; }
    float4 wreg[16];
    const float4* wrow = (const float4*)(W + (size_t)jl * 64);
    #pragma unroll
    for (int k = 0; k < 16; ++k) wreg[k] = wrow[k];
    const float b = bias[jl];
    #pragma unroll
    for (int s = 0; s < 8; ++s) {
        const int tl = (tid & 3) + s * 4;
        const float4* e4 = (const float4*)&se[tl * 64];
        float a = b;
        #pragma unroll
        for (int k = 0; k < 16; ++k) {
            float4 e = e4[k];
            a += wreg[k].x * e.x + wreg[k].y * e.y + wreg[k].z * e.z + wreg[k].w * e.w;
        }
        outp[(size_t)jl * 128 + tbase + tl] = a;
    }
}

// ---------------- main: LDS-FREE transposed GEMM + tree ----------------
// 32x32x16 MFMA; fragments loaded straight from fragment-major global layout:
// one global_load_dwordx4 per fragment (wave-uniform base + lane*16), NO LDS,
// NO barriers -> compiler emits an AITER-style vmcnt(N)-pipelined K-loop.
// C-layout (m74/m101): col = lane&31 (time), row = (reg&3) + 8*(reg>>2) + 4*(lane>>5).
// leaf = fm*32 + 8*s2 + 4*h + l -> l,s2 in-register; jj = 2*(s2&1)+h (1 shuffle);
// i = fm*2 + (s2>>1) in-register.  (epilogue identical to verified R7)
__global__ __launch_bounds__(256, 3)
void fused_gemm_tree(const unsigned short* __restrict__ Wbf2,  // [512][24][64][8]
                     const unsigned short* __restrict__ Abf2,  // [64][24][64][8]
                     const float* __restrict__ ba,
                     const float* __restrict__ tp3T, const float* __restrict__ tp2T,
                     const float* __restrict__ tp1T,
                     const float* __restrict__ w3, const float* __restrict__ w2,
                     const float* __restrict__ w1,
                     float* __restrict__ out) {
    const int tid  = threadIdx.x;
    const int wave = tid >> 6;
    const int lane = tid & 63;
    const int wr = wave >> 1;          // node half: n = blockIdx.x*2 + wr
    const int wc = wave & 1;           // time half
    const int lane31 = lane & 31;
    const int h = lane >> 5;

    const int node0 = blockIdx.x * 128;
    const int m0    = blockIdx.y * 128;

    f32x16 acc[2][2];
    #pragma unroll
    for (int fm = 0; fm < 2; ++fm)
        #pragma unroll
        for (int cf = 0; cf < 2; ++cf)
            #pragma unroll
            for (int r = 0; r < 16; ++r) acc[fm][cf][r] = 0.0f;

    // wave-uniform fragment stream bases (24 kpairs x 512 shorts each)
    const unsigned short* aW0 = Wbf2 + (size_t)(blockIdx.x * 4 + wr * 2 + 0) * 24 * 512;
    const unsigned short* aW1 = aW0 + 24 * 512;
    const unsigned short* aA0 = Abf2 + (size_t)(blockIdx.y * 4 + wc * 2 + 0) * 24 * 512;
    const unsigned short* aA1 = aA0 + 24 * 512;
    const int lo = lane * 8;   // shorts

    #pragma unroll
    for (int kp = 0; kp < 24; ++kp) {
        const int off = kp * 512 + lo;
        bf16x8 af0 = *(const bf16x8*)(aW0 + off);
        bf16x8 af1 = *(const bf16x8*)(aW1 + off);
        bf16x8 bf0 = *(const bf16x8*)(aA0 + off);
        bf16x8 bf1 = *(const bf16x8*)(aA1 + off);
        acc[0][0] = __builtin_amdgcn_mfma_f32_32x32x16_bf16(af0, bf0, acc[0][0], 0, 0, 0);
        acc[0][1] = __builtin_amdgcn_mfma_f32_32x32x16_bf16(af0, bf1, acc[0][1], 0, 0, 0);
        acc[1][0] = __builtin_amdgcn_mfma_f32_32x32x16_bf16(af1, bf0, acc[1][0], 0, 0, 0);
        acc[1][1] = __builtin_amdgcn_mfma_f32_32x32x16_bf16(af1, bf1, acc[1][1], 0, 0, 0);
    }

    // ---- epilogue: softplus + 4/4/4 tree (identical to verified R7) ----
    const int n = blockIdx.x * 2 + wr;
    const int t0 = wc * 64 + lane31;                   // + cf*32 -> t

    float4 bav[2][4], w3v[2][4];
    #pragma unroll
    for (int fm = 0; fm < 2; ++fm)
        #pragma unroll
        for (int s2 = 0; s2 < 4; ++s2) {
            const int leafbase = fm * 32 + 8 * s2 + 4 * h;
            bav[fm][s2] = *(const float4*)&ba[node0 + wr * 64 + leafbase];
            w3v[fm][s2] = *(const float4*)&w3[n * 64 + leafbase];
        }
    float w2v[4][2], w1v[4];                            // [i][s2b] , jj = 2*s2b + h
    #pragma unroll
    for (int i = 0; i < 4; ++i) {
        #pragma unroll
        for (int s2b = 0; s2b < 2; ++s2b)
            w2v[i][s2b] = w2[n * 16 + i * 4 + 2 * s2b + h];
        w1v[i] = w1[n * 4 + i];
    }
    float tp3v[2][2][4], tp2v[2][2][2], tp1v[2];
    #pragma unroll
    for (int fm = 0; fm < 2; ++fm)
        #pragma unroll
        for (int cf = 0; cf < 2; ++cf) {
            const int t = t0 + cf * 32;
            #pragma unroll
            for (int s2 = 0; s2 < 4; ++s2) {
                const int i  = fm * 2 + (s2 >> 1);
                const int jj = 2 * (s2 & 1) + h;
                tp3v[fm][cf][s2] = tp3T[(size_t)((n * 4 + i) * 4 + jj) * 128 + t];
            }
            #pragma unroll
            for (int b = 0; b < 2; ++b)
                tp2v[fm][cf][b] = tp2T[(size_t)(n * 4 + fm * 2 + b) * 128 + t];
        }
    #pragma unroll
    for (int cf = 0; cf < 2; ++cf) tp1v[cf] = tp1T[(size_t)n * 128 + t0 + cf * 32];

    float s1[2] = {0.0f, 0.0f};
    #pragma unroll
    for (int fm = 0; fm < 2; ++fm) {
        #pragma unroll
        for (int cf = 0; cf < 2; ++cf) {
            #pragma unroll
            for (int b = 0; b < 2; ++b) {               // i = fm*2 + b
                float cs = 0.0f;
                #pragma unroll
                for (int s2b = 0; s2b < 2; ++s2b) {
                    const int s2 = 2 * b + s2b;
                    float p3 = 0.0f;
                    const float* bv = (const float*)&bav[fm][s2];
                    const float* wv = (const float*)&w3v[fm][s2];
                    #pragma unroll
                    for (int l = 0; l < 4; ++l) {
                        float a0 = softplus_f(acc[fm][cf][s2 * 4 + l] + bv[l]);
                        p3 = fmaf(a0, wv[l], p3);
                    }
                    float a3 = softplus_f(p3 + tp3v[fm][cf][s2]);
                    cs = fmaf(a3, w2v[fm * 2 + b][s2b], cs);
                }
                float Q = cs + __shfl_xor(cs, 32);      // jj-sum across halves
                float a2 = softplus_f(Q + tp2v[fm][cf][b]);
                s1[cf] = fmaf(a2, w1v[fm * 2 + b], s1[cf]);
            }
        }
    }
    // half h stores cf = h (s1 identical in both halves): 64 unique (t, n)
    {
        const float sj = h ? s1[1] : s1[0];
        const float tq = h ? tp1v[1] : tp1v[0];
        const int t = t0 + h * 32;
        out[(size_t)(m0 + t) * 256 + n] = softplus_f(sj + tq);
    }
}

// ---------------- launcher ----------------
extern "C" void kernel_launch(void* const* d_in, const int* in_sizes, int n_in,
                              void* d_out, int out_size, void* d_ws, size_t ws_size,
                              hipStream_t stream) {
    const float* x    = (const float*)d_in[0];
    const float* temb = (const float*)d_in[1];
    const float* iv   = (const float*)d_in[2];
    const float* Wa   = (const float*)d_in[3];
    const float* ba   = (const float*)d_in[4];
    const float* Wt   = (const float*)d_in[5];
    const float* Wi   = (const float*)d_in[6];
    const float* w3   = (const float*)d_in[7];
    const float* tW3  = (const float*)d_in[8];
    const float* tb3  = (const float*)d_in[9];
    const float* w2   = (const float*)d_in[10];
    const float* tW2  = (const float*)d_in[11];
    const float* tb2  = (const float*)d_in[12];
    const float* w1   = (const float*)d_in[13];
    const float* tW1  = (const float*)d_in[14];
    const float* tb1  = (const float*)d_in[15];
    float* out = (float*)d_out;

    char* ws = (char*)d_ws;
    unsigned short* Abf2 = (unsigned short*)(ws);             //  [64][24][64][8]  bf16 (1.57 MB)
    unsigned short* Wbf2 = (unsigned short*)(ws + 1572864);   //  [512][24][64][8] bf16 (12.58 MB)
    float* tp3T = (float*)(ws + 14155776);                    //  [4096][128]
    float* tp2T = (float*)(ws + 16252928);                    //  [1024][128]
    float* tp1T = (float*)(ws + 16777216);                    //  [256][128]

    repack<<<dim3(REPACK_BLOCKS), dim3(256), 0, stream>>>(x, iv, temb, Wa, Wi, Wt, Abf2);
    tproj<<<dim3(84, 4), dim3(256), 0, stream>>>(temb, tW3, tb3, tW2, tb2, tW1, tb1,
                                                 tp3T, tp2T, tp1T);
    fused_gemm_tree<<<dim3(128, 16), dim3(256), 0, stream>>>(Wbf2, Abf2, ba, tp3T, tp2T, tp1T,
                                                             w3, w2, w1, out);
}